// Round 14
// baseline (40.905 us; speedup 1.0000x reference)
//
#include <hip/hip_runtime.h>
#include <hip/hip_bf16.h>
#include <math.h>

#define NNODES   100000
#define S        8192
#define D        8
#define EPSF     1e-6f
#define LOG2E    1.442695040888963f
#define EPS_S    (LOG2E * EPSF)
#define NT2      256        // 8192/32 tiles per dim

// ws byte offsets
#define ZHL_OFF  0          // 8192 rows x 16 ushort (hi[8]|lo[8]) = 262144 B
#define U_OFF    262144     // 8192 f32
#define V_OFF    294912     // 8192 f32
#define ZB_OFF   327680     // 100000 rows x 8 bf16 = 1.6 MB
#define SP_OFF   1928192    // 2048 f32 sparse partials
#define BK_OFF   1936384    // bucket region
// bucket region layout (128-B stride each):
//   dbuck[64] doubles @ +0 ; cbuck[64] uints @ +64*128 ; gdone @ +128*128

#define NSBLK    2048       // sparse blocks (dedicated kernel)
#define NDBLK    1024       // dense blocks = 128 row-pairs x 8
#define NWPP     32         // waves per row-pair

typedef __attribute__((ext_vector_type(8)))  short short8_t;
typedef __attribute__((ext_vector_type(16))) float f32x16;

__device__ __forceinline__ float block_reduce_f(float v, float* sm) {
    #pragma unroll
    for (int off = 32; off > 0; off >>= 1) v += __shfl_down(v, off, 64);
    int lane = threadIdx.x & 63, wid = threadIdx.x >> 6;
    if (lane == 0) sm[wid] = v;
    __syncthreads();
    float s = 0.f;
    if (threadIdx.x == 0) {
        for (int w = 0; w < 4; ++w) s += sm[w];
    }
    return s;
}

// ---- kernel 1: sample-gather (prescaled hi/lo split) + full-Z bf16 copy ----
__global__ __launch_bounds__(256) void gather_kernel(const float* __restrict__ Z,
                                                     const int* __restrict__ idx,
                                                     ushort* __restrict__ zhl,
                                                     float* __restrict__ u,
                                                     float* __restrict__ v,
                                                     ushort* __restrict__ zb16,
                                                     char* __restrict__ buckets) {
    int gid = blockIdx.x * 256 + threadIdx.x;

    if (blockIdx.x == 0 && threadIdx.x < 129) {
        *(double*)(buckets + threadIdx.x * 128) = 0.0;   // dbuck + cbuck + gdone
    }

    if (gid < S) {
        int n = idx[gid];
        const float4* zp = (const float4*)(Z + (size_t)n * D);
        float4 a = zp[0], b = zp[1];
        float z[8] = { a.x, a.y, a.z, a.w, b.x, b.y, b.z, b.w };
        float ss = 0.f;
        short8_t h, l;
        #pragma unroll
        for (int k = 0; k < 8; ++k) {
            float zs = LOG2E * z[k];
            ss = fmaf(zs, zs, ss);
            __hip_bfloat16 hb = __float2bfloat16(zs);
            float hf = __bfloat162float(hb);
            __hip_bfloat16 lb = __float2bfloat16(zs - hf);
            h[k] = (short)__builtin_bit_cast(unsigned short, hb);
            l[k] = (short)__builtin_bit_cast(unsigned short, lb);
        }
        *(short8_t*)(zhl + (size_t)gid * 16)     = h;
        *(short8_t*)(zhl + (size_t)gid * 16 + 8) = l;
        u[gid] = ss + 8.f * EPS_S * EPS_S;
        v[gid] = ss;
    }

    if (gid < NNODES) {
        const float4* zp = (const float4*)(Z + (size_t)gid * D);
        float4 a = zp[0], b = zp[1];
        float z[8] = { a.x, a.y, a.z, a.w, b.x, b.y, b.z, b.w };
        short8_t o;
        #pragma unroll
        for (int k = 0; k < 8; ++k) {
            __hip_bfloat16 bb = __float2bfloat16(z[k]);
            o[k] = (short)__builtin_bit_cast(unsigned short, bb);
        }
        *(short8_t*)(zb16 + (size_t)gid * 8) = o;
    }
}

// bf16 row (uint4) -> 8 f32
#define UNPACK8(u4, f)                                        \
    f[0] = __uint_as_float(u4.x << 16);                       \
    f[1] = __uint_as_float(u4.x & 0xffff0000u);               \
    f[2] = __uint_as_float(u4.y << 16);                       \
    f[3] = __uint_as_float(u4.y & 0xffff0000u);               \
    f[4] = __uint_as_float(u4.z << 16);                       \
    f[5] = __uint_as_float(u4.z & 0xffff0000u);               \
    f[6] = __uint_as_float(u4.w << 16);                       \
    f[7] = __uint_as_float(u4.w & 0xffff0000u);

// 8 edges: issue all 16 row-gathers, then compute.
__device__ __forceinline__ float edge_dist8(const uint4* __restrict__ zb,
                                            int4 ia0, int4 ia1, int4 ib0, int4 ib1) {
    int aidx[8] = { ia0.x, ia0.y, ia0.z, ia0.w, ia1.x, ia1.y, ia1.z, ia1.w };
    int bidx[8] = { ib0.x, ib0.y, ib0.z, ib0.w, ib1.x, ib1.y, ib1.z, ib1.w };
    uint4 ua[8], ub[8];
    #pragma unroll
    for (int q = 0; q < 8; ++q) { ua[q] = zb[aidx[q]]; ub[q] = zb[bidx[q]]; }
    float acc = 0.f;
    #pragma unroll
    for (int q = 0; q < 8; ++q) {
        float fa[8], fb[8];
        UNPACK8(ua[q], fa);
        UNPACK8(ub[q], fb);
        float s2 = 0.f;
        #pragma unroll
        for (int k = 0; k < 8; ++k) {
            float d = fa[k] - fb[k] + EPSF;
            s2 = fmaf(d, d, s2);
        }
        acc += __builtin_amdgcn_sqrtf(s2);
    }
    return acc;
}

// ---- kernel 2: sparse positive-edge term, dedicated full-device kernel ----
__global__ __launch_bounds__(256) void sparse_kernel(
        const ushort* __restrict__ zb16, const int* __restrict__ ei,
        const int* __restrict__ ej, int ne, float* __restrict__ spart) {
    __shared__ float red[4];
    int tid = threadIdx.x, bx = blockIdx.x;
    const uint4* zb = (const uint4*)zb16;
    const int4* ei4 = (const int4*)ei;
    const int4* ej4 = (const int4*)ej;
    float acc = 0.f;
    int nchunk = ne >> 3;
    int stride = NSBLK * 256;
    int c = bx * 256 + tid;
    if (c < nchunk) {
        int4 ia0 = ei4[2*c], ia1 = ei4[2*c+1];
        int4 ib0 = ej4[2*c], ib1 = ej4[2*c+1];
        while (true) {
            int cn = c + stride;
            bool more = cn < nchunk;
            int4 na0, na1, nb0, nb1;
            if (more) {
                na0 = ei4[2*cn]; na1 = ei4[2*cn+1];
                nb0 = ej4[2*cn]; nb1 = ej4[2*cn+1];
            }
            acc += edge_dist8(zb, ia0, ia1, ib0, ib1);
            if (!more) break;
            ia0 = na0; ia1 = na1; ib0 = nb0; ib1 = nb1; c = cn;
        }
    }
    // tail (ne % 8)
    for (int e = (nchunk << 3) + bx * 256 + tid; e < ne; e += stride) {
        uint4 ua = zb[ei[e]];
        uint4 ub = zb[ej[e]];
        float fa[8], fb[8];
        UNPACK8(ua, fa);
        UNPACK8(ub, fb);
        float s2 = 0.f;
        #pragma unroll
        for (int k = 0; k < 8; ++k) {
            float d = fa[k] - fb[k] + EPSF;
            s2 = fmaf(d, d, s2);
        }
        acc += __builtin_amdgcn_sqrtf(s2);
    }
    float s = block_reduce_f(acc, red);
    if (tid == 0) spart[bx] = s;
}

// Sweep `cnt` consecutive 32x32 j-tiles starting at tj0 for fixed i-tile ti.
// Hi/lo exact product via 2 chained MFMAs. Off-diag tiles weight 2, diag 1.
// C/D: col = lane&31, row = (reg&3) + 8*(reg>>2) + 4*(lane>>5).
__device__ __forceinline__ void dense_sweep32(const ushort* __restrict__ zhl,
                                              const float* __restrict__ v,
                                              short8_t afrag, const float4* u4,
                                              int ti, int tj0, int cnt, int c31,
                                              float& ax, float& ay, float& az, float& aw) {
    const ushort* bp = zhl + (size_t)(tj0 * 32 + c31) * 16;
    const float*  vp = v + tj0 * 32 + c31;
    short8_t bh = *(const short8_t*)bp;
    short8_t bl = *(const short8_t*)(bp + 8);
    float    vt = vp[0];
    #pragma unroll 2
    for (int t = 0; t < cnt; ++t) {
        short8_t bhc = bh, blc = bl;
        float    vtc = vt;
        if (t + 1 < cnt) {
            bh = *(const short8_t*)(bp + (size_t)(t + 1) * 512);
            bl = *(const short8_t*)(bp + (size_t)(t + 1) * 512 + 8);
            vt = vp[(t + 1) * 32];
        }
        float w = (tj0 + t == ti) ? 1.f : 2.f;
        f32x16 c = { 0.f, 0.f, 0.f, 0.f, 0.f, 0.f, 0.f, 0.f,
                     0.f, 0.f, 0.f, 0.f, 0.f, 0.f, 0.f, 0.f };
        c = __builtin_amdgcn_mfma_f32_32x32x16_bf16(afrag, bhc, c, 0, 0, 0);
        c = __builtin_amdgcn_mfma_f32_32x32x16_bf16(afrag, blc, c, 0, 0, 0);
        #pragma unroll
        for (int q = 0; q < 4; ++q) {
            float s0 = u4[q].x + vtc, s1 = u4[q].y + vtc;
            float s2 = u4[q].z + vtc, s3 = u4[q].w + vtc;
            float d0 = fmaf(c[4*q+0], -2.f, s0);
            float d1 = fmaf(c[4*q+1], -2.f, s1);
            float d2 = fmaf(c[4*q+2], -2.f, s2);
            float d3 = fmaf(c[4*q+3], -2.f, s3);
            ax = fmaf(w, __builtin_amdgcn_exp2f(-__builtin_amdgcn_sqrtf(__builtin_fabsf(d0))), ax);
            ay = fmaf(w, __builtin_amdgcn_exp2f(-__builtin_amdgcn_sqrtf(__builtin_fabsf(d1))), ay);
            az = fmaf(w, __builtin_amdgcn_exp2f(-__builtin_amdgcn_sqrtf(__builtin_fabsf(d2))), az);
            aw = fmaf(w, __builtin_amdgcn_exp2f(-__builtin_amdgcn_sqrtf(__builtin_fabsf(d3))), aw);
        }
    }
}

// ---- kernel 3: dense 32x32 triangle; bucketed finalize composes output ----
__global__ __launch_bounds__(256) void dense_kernel(
        const ushort* __restrict__ zhl, const float* __restrict__ u,
        const float* __restrict__ v, const float* __restrict__ alpha,
        const float* __restrict__ spart, char* __restrict__ buckets,
        float* __restrict__ out, int ne) {
    __shared__ float red[4];
    __shared__ unsigned composeFlag;
    int tid = threadIdx.x, bx = blockIdx.x;
    int wave = tid >> 6, lane = tid & 63;
    int g = lane >> 5, c31 = lane & 31;

    int p  = bx >> 3;                        // row-pair index [0,128)
    int wv = (bx & 7) * 4 + wave;            // wave within pair [0,32)
    int k0 = (wv * 257) / NWPP;
    int k1 = ((wv + 1) * 257) / NWPP;
    int n1 = NT2 - p;                        // tiles in row ti = p

    float ax = 0.f, ay = 0.f, az = 0.f, aw = 0.f;

    int eA = k1 < n1 ? k1 : n1;
    if (k0 < eA) {
        int ti = p;
        short8_t afrag = *(const short8_t*)(zhl + (size_t)(ti * 32 + c31) * 16 + g * 8);
        float4 u4[4];
        #pragma unroll
        for (int q = 0; q < 4; ++q) u4[q] = *(const float4*)(u + ti * 32 + 8 * q + 4 * g);
        dense_sweep32(zhl, v, afrag, u4, ti, p + k0, eA - k0, c31, ax, ay, az, aw);
    }
    int sB = k0 > n1 ? k0 : n1;
    if (sB < k1) {
        int ti = (NT2 - 1) - p;
        short8_t afrag = *(const short8_t*)(zhl + (size_t)(ti * 32 + c31) * 16 + g * 8);
        float4 u4[4];
        #pragma unroll
        for (int q = 0; q < 4; ++q) u4[q] = *(const float4*)(u + ti * 32 + 8 * q + 4 * g);
        dense_sweep32(zhl, v, afrag, u4, ti, ti + (sB - n1), k1 - sB, c31, ax, ay, az, aw);
    }
    float s = block_reduce_f((ax + ay) + (az + aw), red);

    // ---- bucketed finalize: 64 buckets x 16 blocks, <=16-deep atomic chains ----
    double* dbuck = (double*)(buckets);
    unsigned* gdone = (unsigned*)(buckets + 128 * 128);

    if (tid == 0) {
        int b = bx & 63;
        (void)atomicAdd((double*)((char*)dbuck + b * 128), (double)s);
        __builtin_amdgcn_s_waitcnt(0);                 // sum add complete
        unsigned oc = atomicAdd((unsigned*)(buckets + (64 + b) * 128), 1u);
        unsigned gg = 0xFFFFu;
        if (oc == 15u) {
            __builtin_amdgcn_s_waitcnt(0);
            gg = atomicAdd(gdone, 1u);
        }
        composeFlag = (gg == 63u) ? 1u : 0u;
    }
    __syncthreads();

    if (composeFlag) {
        // all 1024 dense sums completed-before their counter incs, which
        // completed-before the 64 gdone incs observed. spart visible via
        // kernel-boundary flush. Read + compose.
        __shared__ double acc2[2];
        int w = tid >> 6;
        double val = 0.0;
        if (w == 0) val = atomicAdd((double*)((char*)dbuck + lane * 128), 0.0);
        else if (w == 1) {
            for (int k = lane; k < NSBLK; k += 64) val += (double)spart[k];
        }
        #pragma unroll
        for (int off = 32; off > 0; off >>= 1) val += __shfl_down(val, off, 64);
        if (w == 0 && lane == 0) acc2[0] = val;
        if (w == 1 && lane == 0) acc2[1] = val;
        __syncthreads();
        if (tid == 0) {
            double Dsum = acc2[0], Ssum = acc2[1];
            // diagonal entries are exp(-sqrt(8)*eps); subtract exactly
            double trace = (double)S * exp(-sqrt(8.0) * (double)EPSF);
            double offdiag = Dsum - trace;
            double a = (double)alpha[0];
            double z_pdist2 = (double)ne * a - Ssum;
            double z_pdist1 = exp(a) * 0.5 * 7.3890560989306495 * offdiag;
            out[0] = (float)(z_pdist2 - z_pdist1);
        }
    }
}

extern "C" void kernel_launch(void* const* d_in, const int* in_sizes, int n_in,
                              void* d_out, int out_size, void* d_ws, size_t ws_size,
                              hipStream_t stream) {
    const float* latent_Z = (const float*)d_in[0];
    const float* alpha    = (const float*)d_in[1];
    const int*   sidx     = (const int*)d_in[2];
    const int*   ei       = (const int*)d_in[3];
    const int*   ej       = (const int*)d_in[4];
    int ne = in_sizes[3];
    float* out = (float*)d_out;
    char*  ws  = (char*)d_ws;

    ushort* zhl   = (ushort*)(ws + ZHL_OFF);
    float*  u     = (float*)(ws + U_OFF);
    float*  v     = (float*)(ws + V_OFF);
    ushort* zb16  = (ushort*)(ws + ZB_OFF);
    float*  spart = (float*)(ws + SP_OFF);
    char*   bk    = ws + BK_OFF;

    gather_kernel<<<(NNODES + 255) / 256, 256, 0, stream>>>(latent_Z, sidx,
                                                            zhl, u, v, zb16, bk);
    sparse_kernel<<<NSBLK, 256, 0, stream>>>(zb16, ei, ej, ne, spart);
    dense_kernel<<<NDBLK, 256, 0, stream>>>(zhl, u, v, alpha, spart, bk, out, ne);
}

// Round 15
// 30.842 us; speedup vs baseline: 1.3263x; 1.3263x over previous
//
#include <hip/hip_runtime.h>
#include <hip/hip_bf16.h>
#include <math.h>

#define NNODES   100000
#define S        8192
#define D        8
#define EPSF     1e-6f
#define LOG2E    1.442695040888963f
#define EPS_S    (LOG2E * EPSF)
#define NT2      256        // 8192/32 tiles per dim

// ws byte offsets
#define ZBS_OFF  0          // 8193 rows x 8 ushort (row 8192 = zeros) = 131088 B
#define U_OFF    131104     // 8192 f32 (16B aligned)
#define V_OFF    163872     // 8192 f32
#define ZB_OFF   196640     // 100000 rows x 8 bf16 = 1.6 MB
#define BK_OFF   1796736    // bucket region (128-aligned)
// bucket layout (128-B stride): dbuck[64] @+0; sbuck[16] @+64*128;
//   cbuck[80] @+80*128; gdone @+160*128

#define NSBLK    256        // sparse blocks
#define NDBLK    1024       // dense blocks = 128 row-pairs x 8
#define NWPP     32         // waves per row-pair
#define ZROW     8192       // index of the zero row in zbs

typedef __attribute__((ext_vector_type(8)))  short short8_t;
typedef __attribute__((ext_vector_type(16))) float f32x16;

__device__ __forceinline__ float block_reduce_f(float v, float* sm) {
    #pragma unroll
    for (int off = 32; off > 0; off >>= 1) v += __shfl_down(v, off, 64);
    int lane = threadIdx.x & 63, wid = threadIdx.x >> 6;
    if (lane == 0) sm[wid] = v;
    __syncthreads();
    float s = 0.f;
    if (threadIdx.x == 0) {
        for (int w = 0; w < 4; ++w) s += sm[w];
    }
    return s;
}

// ---- kernel 1: sample-gather (prescaled RNE bf16, norms of ROUNDED values)
//      + full-Z bf16 copy; zero-row + bucket init ----
__global__ __launch_bounds__(256) void gather_kernel(const float* __restrict__ Z,
                                                     const int* __restrict__ idx,
                                                     ushort* __restrict__ zbs,
                                                     float* __restrict__ u,
                                                     float* __restrict__ v,
                                                     ushort* __restrict__ zb16,
                                                     char* __restrict__ buckets) {
    int gid = blockIdx.x * 256 + threadIdx.x;

    if (blockIdx.x == 0 && threadIdx.x < 161) {
        *(double*)(buckets + threadIdx.x * 128) = 0.0;
    }
    if (blockIdx.x == 0 && threadIdx.x == 200) {
        short8_t zz = { 0,0,0,0,0,0,0,0 };
        *(short8_t*)(zbs + (size_t)ZROW * 8) = zz;
    }

    if (gid < S) {
        int n = idx[gid];
        const float4* zp = (const float4*)(Z + (size_t)n * D);
        float4 a = zp[0], b = zp[1];
        float z[8] = { a.x, a.y, a.z, a.w, b.x, b.y, b.z, b.w };
        float ss = 0.f;
        short8_t h;
        #pragma unroll
        for (int k = 0; k < 8; ++k) {
            float zs = LOG2E * z[k];
            __hip_bfloat16 hb = __float2bfloat16(zs);
            float hf = __bfloat162float(hb);
            ss = fmaf(hf, hf, ss);              // norm of the ROUNDED value
            h[k] = (short)__builtin_bit_cast(unsigned short, hb);
        }
        *(short8_t*)(zbs + (size_t)gid * 8) = h;
        u[gid] = ss + 8.f * EPS_S * EPS_S;
        v[gid] = ss;
    }

    if (gid < NNODES) {
        const float4* zp = (const float4*)(Z + (size_t)gid * D);
        float4 a = zp[0], b = zp[1];
        float z[8] = { a.x, a.y, a.z, a.w, b.x, b.y, b.z, b.w };
        short8_t o;
        #pragma unroll
        for (int k = 0; k < 8; ++k) {
            __hip_bfloat16 bb = __float2bfloat16(z[k]);
            o[k] = (short)__builtin_bit_cast(unsigned short, bb);
        }
        *(short8_t*)(zb16 + (size_t)gid * 8) = o;
    }
}

// bf16 row (uint4) -> 8 f32
#define UNPACK8(u4, f)                                        \
    f[0] = __uint_as_float(u4.x << 16);                       \
    f[1] = __uint_as_float(u4.x & 0xffff0000u);               \
    f[2] = __uint_as_float(u4.y << 16);                       \
    f[3] = __uint_as_float(u4.y & 0xffff0000u);               \
    f[4] = __uint_as_float(u4.z << 16);                       \
    f[5] = __uint_as_float(u4.z & 0xffff0000u);               \
    f[6] = __uint_as_float(u4.w << 16);                       \
    f[7] = __uint_as_float(u4.w & 0xffff0000u);

// 8 edges: issue all 16 row-gathers, then compute.
__device__ __forceinline__ float edge_dist8(const uint4* __restrict__ zb,
                                            int4 ia0, int4 ia1, int4 ib0, int4 ib1) {
    int aidx[8] = { ia0.x, ia0.y, ia0.z, ia0.w, ia1.x, ia1.y, ia1.z, ia1.w };
    int bidx[8] = { ib0.x, ib0.y, ib0.z, ib0.w, ib1.x, ib1.y, ib1.z, ib1.w };
    uint4 ua[8], ub[8];
    #pragma unroll
    for (int q = 0; q < 8; ++q) { ua[q] = zb[aidx[q]]; ub[q] = zb[bidx[q]]; }
    float acc = 0.f;
    #pragma unroll
    for (int q = 0; q < 8; ++q) {
        float fa[8], fb[8];
        UNPACK8(ua[q], fa);
        UNPACK8(ub[q], fb);
        float s2 = 0.f;
        #pragma unroll
        for (int k = 0; k < 8; ++k) {
            float d = fa[k] - fb[k] + EPSF;
            s2 = fmaf(d, d, s2);
        }
        acc += __builtin_amdgcn_sqrtf(s2);
    }
    return acc;
}

// Sweep `cnt` consecutive 32x32 j-tiles starting at tj0 for fixed i-tile ti.
// Plain bf16: ONE MFMA per tile. B k-slots [8,16) come from the zero row
// (g=1 lanes), so A's upper half is don't-care. Off-diag weight 2, diag 1.
// C/D: col = lane&31, row = (reg&3) + 8*(reg>>2) + 4*(lane>>5).
__device__ __forceinline__ void dense_sweep32(const ushort* __restrict__ zbs,
                                              const float* __restrict__ v,
                                              short8_t afrag, const float4* u4,
                                              int ti, int tj0, int cnt, int c31, int g,
                                              float& ax, float& ay, float& az, float& aw) {
    const ushort* bp = zbs + (size_t)(g ? ZROW : (tj0 * 32 + c31)) * 8;
    size_t step = g ? 0 : 256;                 // ushorts per tile advance
    const float* vp = v + tj0 * 32 + c31;
    short8_t bnext = *(const short8_t*)bp;
    float    vnext = vp[0];
    #pragma unroll 4
    for (int t = 0; t < cnt; ++t) {
        short8_t bc = bnext;
        float    vtc = vnext;
        if (t + 1 < cnt) {
            bnext = *(const short8_t*)(bp + (size_t)(t + 1) * step);
            vnext = vp[(t + 1) * 32];
        }
        float w = (tj0 + t == ti) ? 1.f : 2.f;
        f32x16 c = { 0.f, 0.f, 0.f, 0.f, 0.f, 0.f, 0.f, 0.f,
                     0.f, 0.f, 0.f, 0.f, 0.f, 0.f, 0.f, 0.f };
        c = __builtin_amdgcn_mfma_f32_32x32x16_bf16(afrag, bc, c, 0, 0, 0);
        #pragma unroll
        for (int q = 0; q < 4; ++q) {
            float s0 = u4[q].x + vtc, s1 = u4[q].y + vtc;
            float s2 = u4[q].z + vtc, s3 = u4[q].w + vtc;
            float d0 = fmaf(c[4*q+0], -2.f, s0);
            float d1 = fmaf(c[4*q+1], -2.f, s1);
            float d2 = fmaf(c[4*q+2], -2.f, s2);
            float d3 = fmaf(c[4*q+3], -2.f, s3);
            ax = fmaf(w, __builtin_amdgcn_exp2f(-__builtin_amdgcn_sqrtf(__builtin_fabsf(d0))), ax);
            ay = fmaf(w, __builtin_amdgcn_exp2f(-__builtin_amdgcn_sqrtf(__builtin_fabsf(d1))), ay);
            az = fmaf(w, __builtin_amdgcn_exp2f(-__builtin_amdgcn_sqrtf(__builtin_fabsf(d2))), az);
            aw = fmaf(w, __builtin_amdgcn_exp2f(-__builtin_amdgcn_sqrtf(__builtin_fabsf(d3))), aw);
        }
    }
}

// ---- kernel 2: sparse || dense 32x32 triangle; bucketed atomic finalize ----
__global__ __launch_bounds__(256) void fused_kernel(
        const ushort* __restrict__ zbs, const float* __restrict__ u,
        const float* __restrict__ v, const ushort* __restrict__ zb16,
        const int* __restrict__ ei, const int* __restrict__ ej, int ne,
        const float* __restrict__ alpha, char* __restrict__ buckets,
        float* __restrict__ out) {
    __shared__ float red[4];
    __shared__ unsigned composeFlag;
    int tid = threadIdx.x, bx = blockIdx.x;
    float s;

    if (bx < NSBLK) {
        // ---- sparse positive-edge term: 8-edge chunks, 16 gathers in flight ----
        const uint4* zb = (const uint4*)zb16;
        const int4* ei4 = (const int4*)ei;
        const int4* ej4 = (const int4*)ej;
        float acc = 0.f;
        int nchunk = ne >> 3;
        int stride = NSBLK * 256;
        int c = bx * 256 + tid;
        if (c < nchunk) {
            int4 ia0 = ei4[2*c], ia1 = ei4[2*c+1];
            int4 ib0 = ej4[2*c], ib1 = ej4[2*c+1];
            while (true) {
                int cn = c + stride;
                bool more = cn < nchunk;
                int4 na0, na1, nb0, nb1;
                if (more) {
                    na0 = ei4[2*cn]; na1 = ei4[2*cn+1];
                    nb0 = ej4[2*cn]; nb1 = ej4[2*cn+1];
                }
                acc += edge_dist8(zb, ia0, ia1, ib0, ib1);
                if (!more) break;
                ia0 = na0; ia1 = na1; ib0 = nb0; ib1 = nb1; c = cn;
            }
        }
        for (int e = (nchunk << 3) + bx * 256 + tid; e < ne; e += stride) {
            uint4 ua = zb[ei[e]];
            uint4 ub = zb[ej[e]];
            float fa[8], fb[8];
            UNPACK8(ua, fa);
            UNPACK8(ub, fb);
            float s2 = 0.f;
            #pragma unroll
            for (int k = 0; k < 8; ++k) {
                float d = fa[k] - fb[k] + EPSF;
                s2 = fmaf(d, d, s2);
            }
            acc += __builtin_amdgcn_sqrtf(s2);
        }
        s = block_reduce_f(acc, red);
    } else {
        // ---- dense term (upper-triangle 32x32 tiles, row-paired) ----
        int dbx  = bx - NSBLK;
        int wave = tid >> 6, lane = tid & 63;
        int g = lane >> 5, c31 = lane & 31;

        int p  = dbx >> 3;                       // row-pair index [0,128)
        int wv = (dbx & 7) * 4 + wave;           // wave within pair [0,32)
        int k0 = (wv * 257) / NWPP;
        int k1 = ((wv + 1) * 257) / NWPP;
        int n1 = NT2 - p;                        // tiles in row ti = p

        float ax = 0.f, ay = 0.f, az = 0.f, aw = 0.f;

        int eA = k1 < n1 ? k1 : n1;
        if (k0 < eA) {
            int ti = p;
            short8_t afrag = *(const short8_t*)(zbs + (size_t)(ti * 32 + c31) * 8);
            float4 u4[4];
            #pragma unroll
            for (int q = 0; q < 4; ++q) u4[q] = *(const float4*)(u + ti * 32 + 8 * q + 4 * g);
            dense_sweep32(zbs, v, afrag, u4, ti, p + k0, eA - k0, c31, g, ax, ay, az, aw);
        }
        int sB = k0 > n1 ? k0 : n1;
        if (sB < k1) {
            int ti = (NT2 - 1) - p;
            short8_t afrag = *(const short8_t*)(zbs + (size_t)(ti * 32 + c31) * 8);
            float4 u4[4];
            #pragma unroll
            for (int q = 0; q < 4; ++q) u4[q] = *(const float4*)(u + ti * 32 + 8 * q + 4 * g);
            dense_sweep32(zbs, v, afrag, u4, ti, ti + (sB - n1), k1 - sB, c31, g, ax, ay, az, aw);
        }
        s = block_reduce_f((ax + ay) + (az + aw), red);
    }

    // ---- bucketed finalize: 80 buckets x 16 blocks, <=16-deep atomic chains ----
    double* dbuck = (double*)(buckets);
    double* sbuck = (double*)(buckets + 64 * 128);
    unsigned* gdone = (unsigned*)(buckets + 160 * 128);

    if (tid == 0) {
        int  sparse = (bx < NSBLK);
        int  sid = sparse ? (bx & 15) : ((bx - NSBLK) & 63);
        int  cid = sparse ? (64 + (bx >> 4)) : ((bx - NSBLK) >> 4);
        double* sumslot = sparse ? (double*)((char*)sbuck + sid * 128)
                                 : (double*)((char*)dbuck + sid * 128);
        (void)atomicAdd(sumslot, (double)s);
        __builtin_amdgcn_s_waitcnt(0);                 // sum add complete
        unsigned oc = atomicAdd((unsigned*)(buckets + (80 + cid) * 128), 1u);
        unsigned g = 0xFFFFu;
        if (oc == 15u) {
            __builtin_amdgcn_s_waitcnt(0);
            g = atomicAdd(gdone, 1u);
        }
        composeFlag = (g == 79u) ? 1u : 0u;
    }
    __syncthreads();

    if (composeFlag) {
        __shared__ double acc2[2];
        int lane = tid & 63, w = tid >> 6;
        double val = 0.0;
        if (w == 0) val = atomicAdd((double*)((char*)dbuck + lane * 128), 0.0);
        else if (w == 1 && lane < 16) val = atomicAdd((double*)((char*)sbuck + lane * 128), 0.0);
        #pragma unroll
        for (int off = 32; off > 0; off >>= 1) val += __shfl_down(val, off, 64);
        if (w == 0 && lane == 0) acc2[0] = val;
        if (w == 1 && lane == 0) acc2[1] = val;
        __syncthreads();
        if (tid == 0) {
            double Dsum = acc2[0], Ssum = acc2[1];
            double trace = (double)S * exp(-sqrt(8.0) * (double)EPSF);
            double offdiag = Dsum - trace;
            double a = (double)alpha[0];
            double z_pdist2 = (double)ne * a - Ssum;
            double z_pdist1 = exp(a) * 0.5 * 7.3890560989306495 * offdiag;
            out[0] = (float)(z_pdist2 - z_pdist1);
        }
    }
}

extern "C" void kernel_launch(void* const* d_in, const int* in_sizes, int n_in,
                              void* d_out, int out_size, void* d_ws, size_t ws_size,
                              hipStream_t stream) {
    const float* latent_Z = (const float*)d_in[0];
    const float* alpha    = (const float*)d_in[1];
    const int*   sidx     = (const int*)d_in[2];
    const int*   ei       = (const int*)d_in[3];
    const int*   ej       = (const int*)d_in[4];
    int ne = in_sizes[3];
    float* out = (float*)d_out;
    char*  ws  = (char*)d_ws;

    ushort* zbs   = (ushort*)(ws + ZBS_OFF);
    float*  u     = (float*)(ws + U_OFF);
    float*  v     = (float*)(ws + V_OFF);
    ushort* zb16  = (ushort*)(ws + ZB_OFF);
    char*   bk    = ws + BK_OFF;

    gather_kernel<<<(NNODES + 255) / 256, 256, 0, stream>>>(latent_Z, sidx,
                                                            zbs, u, v, zb16, bk);
    fused_kernel<<<NSBLK + NDBLK, 256, 0, stream>>>(zbs, u, v, zb16, ei, ej, ne,
                                                    alpha, bk, out);
}

// Round 16
// 30.580 us; speedup vs baseline: 1.3376x; 1.0086x over previous
//
#include <hip/hip_runtime.h>
#include <hip/hip_bf16.h>
#include <math.h>

#define NNODES   100000
#define S        8192
#define D        8
#define EPSF     1e-6f
#define LOG2E    1.442695040888963f
#define EPS_S    (LOG2E * EPSF)
#define NT2      256        // 8192/32 tiles per dim

// ws byte offsets
#define ZBS_OFF  0          // 8193 rows x 8 ushort (row 8192 = zeros)
#define U_OFF    131104     // 8192 f32
#define V_OFF    163872     // 8192 f32
#define ZB_OFF   196640     // 100000 rows x 8 bf16 = 1.6 MB
#define BK_OFF   1796736    // bucket region (128-aligned)
// bucket layout (128-B stride): dbuck[64] @0-63; sbuck[64] @64-127;
//   cbuck[64] @128-191; gdone @192   -> 193 slots

#define NDBLK    1024       // all blocks: sparse thin layer + dense triangle
#define NWPP     32         // waves per row-pair (128 pairs x 8 blocks)
#define ZROW     8192

typedef __attribute__((ext_vector_type(8)))  short short8_t;
typedef __attribute__((ext_vector_type(16))) float f32x16;

// reduce two values across the block
__device__ __forceinline__ void block_reduce_2(float a, float b, float* sma,
                                               float* smb, float& ra, float& rb) {
    #pragma unroll
    for (int off = 32; off > 0; off >>= 1) {
        a += __shfl_down(a, off, 64);
        b += __shfl_down(b, off, 64);
    }
    int lane = threadIdx.x & 63, wid = threadIdx.x >> 6;
    if (lane == 0) { sma[wid] = a; smb[wid] = b; }
    __syncthreads();
    if (threadIdx.x == 0) {
        ra = 0.f; rb = 0.f;
        for (int w = 0; w < 4; ++w) { ra += sma[w]; rb += smb[w]; }
    }
}

// ---- kernel 1: sample-gather (prescaled RNE bf16, norms of ROUNDED values)
//      + full-Z bf16 copy; zero-row + bucket init ----
__global__ __launch_bounds__(256) void gather_kernel(const float* __restrict__ Z,
                                                     const int* __restrict__ idx,
                                                     ushort* __restrict__ zbs,
                                                     float* __restrict__ u,
                                                     float* __restrict__ v,
                                                     ushort* __restrict__ zb16,
                                                     char* __restrict__ buckets) {
    int gid = blockIdx.x * 256 + threadIdx.x;

    if (blockIdx.x == 0 && threadIdx.x < 193) {
        *(double*)(buckets + threadIdx.x * 128) = 0.0;
    }
    if (blockIdx.x == 0 && threadIdx.x == 200) {
        short8_t zz = { 0,0,0,0,0,0,0,0 };
        *(short8_t*)(zbs + (size_t)ZROW * 8) = zz;
    }

    if (gid < S) {
        int n = idx[gid];
        const float4* zp = (const float4*)(Z + (size_t)n * D);
        float4 a = zp[0], b = zp[1];
        float z[8] = { a.x, a.y, a.z, a.w, b.x, b.y, b.z, b.w };
        float ss = 0.f;
        short8_t h;
        #pragma unroll
        for (int k = 0; k < 8; ++k) {
            float zs = LOG2E * z[k];
            __hip_bfloat16 hb = __float2bfloat16(zs);
            float hf = __bfloat162float(hb);
            ss = fmaf(hf, hf, ss);              // norm of the ROUNDED value
            h[k] = (short)__builtin_bit_cast(unsigned short, hb);
        }
        *(short8_t*)(zbs + (size_t)gid * 8) = h;
        u[gid] = ss + 8.f * EPS_S * EPS_S;
        v[gid] = ss;
    }

    if (gid < NNODES) {
        const float4* zp = (const float4*)(Z + (size_t)gid * D);
        float4 a = zp[0], b = zp[1];
        float z[8] = { a.x, a.y, a.z, a.w, b.x, b.y, b.z, b.w };
        short8_t o;
        #pragma unroll
        for (int k = 0; k < 8; ++k) {
            __hip_bfloat16 bb = __float2bfloat16(z[k]);
            o[k] = (short)__builtin_bit_cast(unsigned short, bb);
        }
        *(short8_t*)(zb16 + (size_t)gid * 8) = o;
    }
}

// bf16 row (uint4) -> 8 f32
#define UNPACK8(u4, f)                                        \
    f[0] = __uint_as_float(u4.x << 16);                       \
    f[1] = __uint_as_float(u4.x & 0xffff0000u);               \
    f[2] = __uint_as_float(u4.y << 16);                       \
    f[3] = __uint_as_float(u4.y & 0xffff0000u);               \
    f[4] = __uint_as_float(u4.z << 16);                       \
    f[5] = __uint_as_float(u4.z & 0xffff0000u);               \
    f[6] = __uint_as_float(u4.w << 16);                       \
    f[7] = __uint_as_float(u4.w & 0xffff0000u);

// Sweep `cnt` consecutive 32x32 j-tiles starting at tj0 for fixed i-tile ti.
// Plain bf16: ONE MFMA per tile (B k-slots [8,16) fed from the zero row).
// Off-diag weight 2, diag 1.
// C/D: col = lane&31, row = (reg&3) + 8*(reg>>2) + 4*(lane>>5).
__device__ __forceinline__ void dense_sweep32(const ushort* __restrict__ zbs,
                                              const float* __restrict__ v,
                                              short8_t afrag, const float4* u4,
                                              int ti, int tj0, int cnt, int c31, int g,
                                              float& ax, float& ay, float& az, float& aw) {
    const ushort* bp = zbs + (size_t)(g ? ZROW : (tj0 * 32 + c31)) * 8;
    size_t step = g ? 0 : 256;                 // ushorts per tile advance
    const float* vp = v + tj0 * 32 + c31;
    short8_t bnext = *(const short8_t*)bp;
    float    vnext = vp[0];
    #pragma unroll 4
    for (int t = 0; t < cnt; ++t) {
        short8_t bc = bnext;
        float    vtc = vnext;
        if (t + 1 < cnt) {
            bnext = *(const short8_t*)(bp + (size_t)(t + 1) * step);
            vnext = vp[(t + 1) * 32];
        }
        float w = (tj0 + t == ti) ? 1.f : 2.f;
        f32x16 c = { 0.f, 0.f, 0.f, 0.f, 0.f, 0.f, 0.f, 0.f,
                     0.f, 0.f, 0.f, 0.f, 0.f, 0.f, 0.f, 0.f };
        c = __builtin_amdgcn_mfma_f32_32x32x16_bf16(afrag, bc, c, 0, 0, 0);
        #pragma unroll
        for (int q = 0; q < 4; ++q) {
            float s0 = u4[q].x + vtc, s1 = u4[q].y + vtc;
            float s2 = u4[q].z + vtc, s3 = u4[q].w + vtc;
            float d0 = fmaf(c[4*q+0], -2.f, s0);
            float d1 = fmaf(c[4*q+1], -2.f, s1);
            float d2 = fmaf(c[4*q+2], -2.f, s2);
            float d3 = fmaf(c[4*q+3], -2.f, s3);
            ax = fmaf(w, __builtin_amdgcn_exp2f(-__builtin_amdgcn_sqrtf(__builtin_fabsf(d0))), ax);
            ay = fmaf(w, __builtin_amdgcn_exp2f(-__builtin_amdgcn_sqrtf(__builtin_fabsf(d1))), ay);
            az = fmaf(w, __builtin_amdgcn_exp2f(-__builtin_amdgcn_sqrtf(__builtin_fabsf(d2))), az);
            aw = fmaf(w, __builtin_amdgcn_exp2f(-__builtin_amdgcn_sqrtf(__builtin_fabsf(d3))), aw);
        }
    }
}

// ---- kernel 2: every block = thin sparse layer, then dense triangle;
//      bucketed atomic finalize carries both sums ----
__global__ __launch_bounds__(256) void fused_kernel(
        const ushort* __restrict__ zbs, const float* __restrict__ u,
        const float* __restrict__ v, const ushort* __restrict__ zb16,
        const int* __restrict__ ei, const int* __restrict__ ej, int ne,
        const float* __restrict__ alpha, char* __restrict__ buckets,
        float* __restrict__ out) {
    __shared__ float reda[4], redb[4];
    __shared__ unsigned composeFlag;
    int tid = threadIdx.x, bx = blockIdx.x;

    // ---- phase A: sparse slice (4-edge chunks, 8 gathers in flight) ----
    float sacc = 0.f;
    {
        const uint4* zb = (const uint4*)zb16;
        int nchunk = ne >> 2;
        int stride = NDBLK * 256;
        for (int c = bx * 256 + tid; c < nchunk; c += stride) {
            int4 ia = ((const int4*)ei)[c];
            int4 ib = ((const int4*)ej)[c];
            int aidx[4] = { ia.x, ia.y, ia.z, ia.w };
            int bidx[4] = { ib.x, ib.y, ib.z, ib.w };
            uint4 ua[4], ub[4];
            #pragma unroll
            for (int q = 0; q < 4; ++q) { ua[q] = zb[aidx[q]]; ub[q] = zb[bidx[q]]; }
            #pragma unroll
            for (int q = 0; q < 4; ++q) {
                float fa[8], fb[8];
                UNPACK8(ua[q], fa);
                UNPACK8(ub[q], fb);
                float s2 = 0.f;
                #pragma unroll
                for (int k = 0; k < 8; ++k) {
                    float d = fa[k] - fb[k] + EPSF;
                    s2 = fmaf(d, d, s2);
                }
                sacc += __builtin_amdgcn_sqrtf(s2);
            }
        }
        // tail (ne % 4)
        for (int e = (nchunk << 2) + bx * 256 + tid; e < ne; e += stride) {
            uint4 ua = zb[ei[e]];
            uint4 ub = zb[ej[e]];
            float fa[8], fb[8];
            UNPACK8(ua, fa);
            UNPACK8(ub, fb);
            float s2 = 0.f;
            #pragma unroll
            for (int k = 0; k < 8; ++k) {
                float d = fa[k] - fb[k] + EPSF;
                s2 = fmaf(d, d, s2);
            }
            sacc += __builtin_amdgcn_sqrtf(s2);
        }
    }

    // ---- phase B: dense term (upper-triangle 32x32 tiles, row-paired) ----
    int wave = tid >> 6, lane = tid & 63;
    int g = lane >> 5, c31 = lane & 31;

    int p  = bx >> 3;                        // row-pair index [0,128)
    int wv = (bx & 7) * 4 + wave;            // wave within pair [0,32)
    int k0 = (wv * 257) / NWPP;
    int k1 = ((wv + 1) * 257) / NWPP;
    int n1 = NT2 - p;                        // tiles in row ti = p

    float ax = 0.f, ay = 0.f, az = 0.f, aw = 0.f;

    int eA = k1 < n1 ? k1 : n1;
    if (k0 < eA) {
        int ti = p;
        short8_t afrag = *(const short8_t*)(zbs + (size_t)(ti * 32 + c31) * 8);
        float4 u4[4];
        #pragma unroll
        for (int q = 0; q < 4; ++q) u4[q] = *(const float4*)(u + ti * 32 + 8 * q + 4 * g);
        dense_sweep32(zbs, v, afrag, u4, ti, p + k0, eA - k0, c31, g, ax, ay, az, aw);
    }
    int sB = k0 > n1 ? k0 : n1;
    if (sB < k1) {
        int ti = (NT2 - 1) - p;
        short8_t afrag = *(const short8_t*)(zbs + (size_t)(ti * 32 + c31) * 8);
        float4 u4[4];
        #pragma unroll
        for (int q = 0; q < 4; ++q) u4[q] = *(const float4*)(u + ti * 32 + 8 * q + 4 * g);
        dense_sweep32(zbs, v, afrag, u4, ti, ti + (sB - n1), k1 - sB, c31, g, ax, ay, az, aw);
    }

    float sd = 0.f, ss = 0.f;
    block_reduce_2((ax + ay) + (az + aw), sacc, reda, redb, sd, ss);

    // ---- bucketed finalize: 64+64 sum buckets (16-deep), 64 counters ----
    double* dbuck = (double*)(buckets);
    double* sbuck = (double*)(buckets + 64 * 128);
    unsigned* gdone = (unsigned*)(buckets + 192 * 128);

    if (tid == 0) {
        int b = bx & 63;
        (void)atomicAdd((double*)((char*)dbuck + b * 128), (double)sd);
        (void)atomicAdd((double*)((char*)sbuck + b * 128), (double)ss);
        __builtin_amdgcn_s_waitcnt(0);                 // both adds complete
        unsigned oc = atomicAdd((unsigned*)(buckets + (128 + (bx >> 4)) * 128), 1u);
        unsigned gg = 0xFFFFu;
        if (oc == 15u) {
            __builtin_amdgcn_s_waitcnt(0);
            gg = atomicAdd(gdone, 1u);
        }
        composeFlag = (gg == 63u) ? 1u : 0u;
    }
    __syncthreads();

    if (composeFlag) {
        __shared__ double acc2[2];
        int w = tid >> 6;
        double val = 0.0;
        if (w == 0) val = atomicAdd((double*)((char*)dbuck + lane * 128), 0.0);
        else if (w == 1) val = atomicAdd((double*)((char*)sbuck + lane * 128), 0.0);
        #pragma unroll
        for (int off = 32; off > 0; off >>= 1) val += __shfl_down(val, off, 64);
        if (w == 0 && lane == 0) acc2[0] = val;
        if (w == 1 && lane == 0) acc2[1] = val;
        __syncthreads();
        if (tid == 0) {
            double Dsum = acc2[0], Ssum = acc2[1];
            // diagonal entries are exp(-sqrt(8)*eps); subtract exactly
            double trace = (double)S * exp(-sqrt(8.0) * (double)EPSF);
            double offdiag = Dsum - trace;
            double a = (double)alpha[0];
            double z_pdist2 = (double)ne * a - Ssum;
            double z_pdist1 = exp(a) * 0.5 * 7.3890560989306495 * offdiag;
            out[0] = (float)(z_pdist2 - z_pdist1);
        }
    }
}

extern "C" void kernel_launch(void* const* d_in, const int* in_sizes, int n_in,
                              void* d_out, int out_size, void* d_ws, size_t ws_size,
                              hipStream_t stream) {
    const float* latent_Z = (const float*)d_in[0];
    const float* alpha    = (const float*)d_in[1];
    const int*   sidx     = (const int*)d_in[2];
    const int*   ei       = (const int*)d_in[3];
    const int*   ej       = (const int*)d_in[4];
    int ne = in_sizes[3];
    float* out = (float*)d_out;
    char*  ws  = (char*)d_ws;

    ushort* zbs   = (ushort*)(ws + ZBS_OFF);
    float*  u     = (float*)(ws + U_OFF);
    float*  v     = (float*)(ws + V_OFF);
    ushort* zb16  = (ushort*)(ws + ZB_OFF);
    char*   bk    = ws + BK_OFF;

    gather_kernel<<<(NNODES + 255) / 256, 256, 0, stream>>>(latent_Z, sidx,
                                                            zbs, u, v, zb16, bk);
    fused_kernel<<<NDBLK, 256, 0, stream>>>(zbs, u, v, zb16, ei, ej, ne,
                                            alpha, bk, out);
}

// Round 17
// 30.492 us; speedup vs baseline: 1.3415x; 1.0029x over previous
//
#include <hip/hip_runtime.h>
#include <hip/hip_bf16.h>
#include <math.h>

#define NNODES   100000
#define S        8192
#define D        8
#define EPSF     1e-6f
#define LOG2E    1.442695040888963f
#define EPS_S    (LOG2E * EPSF)
#define NT2      256        // 8192/32 tiles per dim

// ws byte offsets
#define ZBS_OFF  0          // 8193 rows x 8 ushort (row 8192 = zeros)
#define U_OFF    131104     // 8192 f32
#define V_OFF    163872     // 8192 f32
#define ZB_OFF   196640     // 100000 rows x 8 bf16 = 1.6 MB
#define BK_OFF   1796736    // bucket region (128-aligned)
// bucket layout (128-B stride): dbuck[128] @0-127; sbuck[128] @128-255;
//   cbuck[128] @256-383; gdone @384  -> 385 slots

#define NDBLK    2048       // all blocks: sparse thin layer + dense triangle
#define NWPP     64         // waves per row-pair (128 pairs x 16 blocks)
#define ZROW     8192

typedef __attribute__((ext_vector_type(8)))  short short8_t;
typedef __attribute__((ext_vector_type(16))) float f32x16;

// reduce two values across the block
__device__ __forceinline__ void block_reduce_2(float a, float b, float* sma,
                                               float* smb, float& ra, float& rb) {
    #pragma unroll
    for (int off = 32; off > 0; off >>= 1) {
        a += __shfl_down(a, off, 64);
        b += __shfl_down(b, off, 64);
    }
    int lane = threadIdx.x & 63, wid = threadIdx.x >> 6;
    if (lane == 0) { sma[wid] = a; smb[wid] = b; }
    __syncthreads();
    if (threadIdx.x == 0) {
        ra = 0.f; rb = 0.f;
        for (int w = 0; w < 4; ++w) { ra += sma[w]; rb += smb[w]; }
    }
}

// ---- kernel 1: sample-gather (prescaled RNE bf16, norms of ROUNDED values)
//      + full-Z bf16 copy; zero-row + bucket init ----
__global__ __launch_bounds__(256) void gather_kernel(const float* __restrict__ Z,
                                                     const int* __restrict__ idx,
                                                     ushort* __restrict__ zbs,
                                                     float* __restrict__ u,
                                                     float* __restrict__ v,
                                                     ushort* __restrict__ zb16,
                                                     char* __restrict__ buckets) {
    int gid = blockIdx.x * 256 + threadIdx.x;

    if (gid < 385) {
        *(double*)(buckets + (size_t)gid * 128) = 0.0;
    }
    if (blockIdx.x == 2 && threadIdx.x == 0) {
        short8_t zz = { 0,0,0,0,0,0,0,0 };
        *(short8_t*)(zbs + (size_t)ZROW * 8) = zz;
    }

    if (gid < S) {
        int n = idx[gid];
        const float4* zp = (const float4*)(Z + (size_t)n * D);
        float4 a = zp[0], b = zp[1];
        float z[8] = { a.x, a.y, a.z, a.w, b.x, b.y, b.z, b.w };
        float ss = 0.f;
        short8_t h;
        #pragma unroll
        for (int k = 0; k < 8; ++k) {
            float zs = LOG2E * z[k];
            __hip_bfloat16 hb = __float2bfloat16(zs);
            float hf = __bfloat162float(hb);
            ss = fmaf(hf, hf, ss);              // norm of the ROUNDED value
            h[k] = (short)__builtin_bit_cast(unsigned short, hb);
        }
        *(short8_t*)(zbs + (size_t)gid * 8) = h;
        u[gid] = ss + 8.f * EPS_S * EPS_S;
        v[gid] = ss;
    }

    if (gid < NNODES) {
        const float4* zp = (const float4*)(Z + (size_t)gid * D);
        float4 a = zp[0], b = zp[1];
        float z[8] = { a.x, a.y, a.z, a.w, b.x, b.y, b.z, b.w };
        short8_t o;
        #pragma unroll
        for (int k = 0; k < 8; ++k) {
            __hip_bfloat16 bb = __float2bfloat16(z[k]);
            o[k] = (short)__builtin_bit_cast(unsigned short, bb);
        }
        *(short8_t*)(zb16 + (size_t)gid * 8) = o;
    }
}

// bf16 row (uint4) -> 8 f32
#define UNPACK8(u4, f)                                        \
    f[0] = __uint_as_float(u4.x << 16);                       \
    f[1] = __uint_as_float(u4.x & 0xffff0000u);               \
    f[2] = __uint_as_float(u4.y << 16);                       \
    f[3] = __uint_as_float(u4.y & 0xffff0000u);               \
    f[4] = __uint_as_float(u4.z << 16);                       \
    f[5] = __uint_as_float(u4.z & 0xffff0000u);               \
    f[6] = __uint_as_float(u4.w << 16);                       \
    f[7] = __uint_as_float(u4.w & 0xffff0000u);

// Sweep `cnt` consecutive 32x32 j-tiles starting at tj0 for fixed i-tile ti.
// Plain bf16: ONE MFMA per tile (B k-slots [8,16) fed from the zero row).
// Off-diag weight 2, diag 1.
// C/D: col = lane&31, row = (reg&3) + 8*(reg>>2) + 4*(lane>>5).
__device__ __forceinline__ void dense_sweep32(const ushort* __restrict__ zbs,
                                              const float* __restrict__ v,
                                              short8_t afrag, const float4* u4,
                                              int ti, int tj0, int cnt, int c31, int g,
                                              float& ax, float& ay, float& az, float& aw) {
    const ushort* bp = zbs + (size_t)(g ? ZROW : (tj0 * 32 + c31)) * 8;
    size_t step = g ? 0 : 256;                 // ushorts per tile advance
    const float* vp = v + tj0 * 32 + c31;
    short8_t bnext = *(const short8_t*)bp;
    float    vnext = vp[0];
    #pragma unroll 4
    for (int t = 0; t < cnt; ++t) {
        short8_t bc = bnext;
        float    vtc = vnext;
        if (t + 1 < cnt) {
            bnext = *(const short8_t*)(bp + (size_t)(t + 1) * step);
            vnext = vp[(t + 1) * 32];
        }
        float w = (tj0 + t == ti) ? 1.f : 2.f;
        f32x16 c = { 0.f, 0.f, 0.f, 0.f, 0.f, 0.f, 0.f, 0.f,
                     0.f, 0.f, 0.f, 0.f, 0.f, 0.f, 0.f, 0.f };
        c = __builtin_amdgcn_mfma_f32_32x32x16_bf16(afrag, bc, c, 0, 0, 0);
        #pragma unroll
        for (int q = 0; q < 4; ++q) {
            float s0 = u4[q].x + vtc, s1 = u4[q].y + vtc;
            float s2 = u4[q].z + vtc, s3 = u4[q].w + vtc;
            float d0 = fmaf(c[4*q+0], -2.f, s0);
            float d1 = fmaf(c[4*q+1], -2.f, s1);
            float d2 = fmaf(c[4*q+2], -2.f, s2);
            float d3 = fmaf(c[4*q+3], -2.f, s3);
            ax = fmaf(w, __builtin_amdgcn_exp2f(-__builtin_amdgcn_sqrtf(__builtin_fabsf(d0))), ax);
            ay = fmaf(w, __builtin_amdgcn_exp2f(-__builtin_amdgcn_sqrtf(__builtin_fabsf(d1))), ay);
            az = fmaf(w, __builtin_amdgcn_exp2f(-__builtin_amdgcn_sqrtf(__builtin_fabsf(d2))), az);
            aw = fmaf(w, __builtin_amdgcn_exp2f(-__builtin_amdgcn_sqrtf(__builtin_fabsf(d3))), aw);
        }
    }
}

// ---- kernel 2: every block = thin sparse layer, then dense triangle;
//      bucketed atomic finalize carries both sums ----
__global__ __launch_bounds__(256) void fused_kernel(
        const ushort* __restrict__ zbs, const float* __restrict__ u,
        const float* __restrict__ v, const ushort* __restrict__ zb16,
        const int* __restrict__ ei, const int* __restrict__ ej, int ne,
        const float* __restrict__ alpha, char* __restrict__ buckets,
        float* __restrict__ out) {
    __shared__ float reda[4], redb[4];
    __shared__ unsigned composeFlag;
    int tid = threadIdx.x, bx = blockIdx.x;

    // ---- phase A: sparse slice (4-edge chunks, 8 gathers in flight) ----
    float sacc = 0.f;
    {
        const uint4* zb = (const uint4*)zb16;
        int nchunk = ne >> 2;
        int stride = NDBLK * 256;
        for (int c = bx * 256 + tid; c < nchunk; c += stride) {
            int4 ia = ((const int4*)ei)[c];
            int4 ib = ((const int4*)ej)[c];
            int aidx[4] = { ia.x, ia.y, ia.z, ia.w };
            int bidx[4] = { ib.x, ib.y, ib.z, ib.w };
            uint4 ua[4], ub[4];
            #pragma unroll
            for (int q = 0; q < 4; ++q) { ua[q] = zb[aidx[q]]; ub[q] = zb[bidx[q]]; }
            #pragma unroll
            for (int q = 0; q < 4; ++q) {
                float fa[8], fb[8];
                UNPACK8(ua[q], fa);
                UNPACK8(ub[q], fb);
                float s2 = 0.f;
                #pragma unroll
                for (int k = 0; k < 8; ++k) {
                    float d = fa[k] - fb[k] + EPSF;
                    s2 = fmaf(d, d, s2);
                }
                sacc += __builtin_amdgcn_sqrtf(s2);
            }
        }
        // tail (ne % 4)
        for (int e = (nchunk << 2) + bx * 256 + tid; e < ne; e += stride) {
            uint4 ua = zb[ei[e]];
            uint4 ub = zb[ej[e]];
            float fa[8], fb[8];
            UNPACK8(ua, fa);
            UNPACK8(ub, fb);
            float s2 = 0.f;
            #pragma unroll
            for (int k = 0; k < 8; ++k) {
                float d = fa[k] - fb[k] + EPSF;
                s2 = fmaf(d, d, s2);
            }
            sacc += __builtin_amdgcn_sqrtf(s2);
        }
    }

    // ---- phase B: dense term (upper-triangle 32x32 tiles, row-paired) ----
    int wave = tid >> 6, lane = tid & 63;
    int g = lane >> 5, c31 = lane & 31;

    int p  = bx >> 4;                        // row-pair index [0,128)
    int wv = (bx & 15) * 4 + wave;           // wave within pair [0,64)
    int k0 = (wv * 257) / NWPP;
    int k1 = ((wv + 1) * 257) / NWPP;
    int n1 = NT2 - p;                        // tiles in row ti = p

    float ax = 0.f, ay = 0.f, az = 0.f, aw = 0.f;

    int eA = k1 < n1 ? k1 : n1;
    if (k0 < eA) {
        int ti = p;
        short8_t afrag = *(const short8_t*)(zbs + (size_t)(ti * 32 + c31) * 8);
        float4 u4[4];
        #pragma unroll
        for (int q = 0; q < 4; ++q) u4[q] = *(const float4*)(u + ti * 32 + 8 * q + 4 * g);
        dense_sweep32(zbs, v, afrag, u4, ti, p + k0, eA - k0, c31, g, ax, ay, az, aw);
    }
    int sB = k0 > n1 ? k0 : n1;
    if (sB < k1) {
        int ti = (NT2 - 1) - p;
        short8_t afrag = *(const short8_t*)(zbs + (size_t)(ti * 32 + c31) * 8);
        float4 u4[4];
        #pragma unroll
        for (int q = 0; q < 4; ++q) u4[q] = *(const float4*)(u + ti * 32 + 8 * q + 4 * g);
        dense_sweep32(zbs, v, afrag, u4, ti, ti + (sB - n1), k1 - sB, c31, g, ax, ay, az, aw);
    }

    float sd = 0.f, ss = 0.f;
    block_reduce_2((ax + ay) + (az + aw), sacc, reda, redb, sd, ss);

    // ---- bucketed finalize: 128+128 sum buckets (16-deep), 128 counters ----
    double* dbuck = (double*)(buckets);
    double* sbuck = (double*)(buckets + 128 * 128);
    unsigned* gdone = (unsigned*)(buckets + 384 * 128);

    if (tid == 0) {
        int b = bx & 127;
        (void)atomicAdd((double*)((char*)dbuck + b * 128), (double)sd);
        (void)atomicAdd((double*)((char*)sbuck + b * 128), (double)ss);
        __builtin_amdgcn_s_waitcnt(0);                 // both adds complete
        unsigned oc = atomicAdd((unsigned*)(buckets + (256 + (bx >> 4)) * 128), 1u);
        unsigned gg = 0xFFFFu;
        if (oc == 15u) {
            __builtin_amdgcn_s_waitcnt(0);
            gg = atomicAdd(gdone, 1u);
        }
        composeFlag = (gg == 127u) ? 1u : 0u;
    }
    __syncthreads();

    if (composeFlag) {
        __shared__ double acc2[2];
        int w = tid >> 6;
        double val = 0.0;
        if (w == 0) {
            val  = atomicAdd((double*)((char*)dbuck + lane * 128), 0.0);
            val += atomicAdd((double*)((char*)dbuck + (lane + 64) * 128), 0.0);
        } else if (w == 1) {
            val  = atomicAdd((double*)((char*)sbuck + lane * 128), 0.0);
            val += atomicAdd((double*)((char*)sbuck + (lane + 64) * 128), 0.0);
        }
        #pragma unroll
        for (int off = 32; off > 0; off >>= 1) val += __shfl_down(val, off, 64);
        if (w == 0 && lane == 0) acc2[0] = val;
        if (w == 1 && lane == 0) acc2[1] = val;
        __syncthreads();
        if (tid == 0) {
            double Dsum = acc2[0], Ssum = acc2[1];
            // diagonal entries are exp(-sqrt(8)*eps); subtract exactly
            double trace = (double)S * exp(-sqrt(8.0) * (double)EPSF);
            double offdiag = Dsum - trace;
            double a = (double)alpha[0];
            double z_pdist2 = (double)ne * a - Ssum;
            double z_pdist1 = exp(a) * 0.5 * 7.3890560989306495 * offdiag;
            out[0] = (float)(z_pdist2 - z_pdist1);
        }
    }
}

extern "C" void kernel_launch(void* const* d_in, const int* in_sizes, int n_in,
                              void* d_out, int out_size, void* d_ws, size_t ws_size,
                              hipStream_t stream) {
    const float* latent_Z = (const float*)d_in[0];
    const float* alpha    = (const float*)d_in[1];
    const int*   sidx     = (const int*)d_in[2];
    const int*   ei       = (const int*)d_in[3];
    const int*   ej       = (const int*)d_in[4];
    int ne = in_sizes[3];
    float* out = (float*)d_out;
    char*  ws  = (char*)d_ws;

    ushort* zbs   = (ushort*)(ws + ZBS_OFF);
    float*  u     = (float*)(ws + U_OFF);
    float*  v     = (float*)(ws + V_OFF);
    ushort* zb16  = (ushort*)(ws + ZB_OFF);
    char*   bk    = ws + BK_OFF;

    gather_kernel<<<(NNODES + 255) / 256, 256, 0, stream>>>(latent_Z, sidx,
                                                            zbs, u, v, zb16, bk);
    fused_kernel<<<NDBLK, 256, 0, stream>>>(zbs, u, v, zb16, ei, ej, ne,
                                            alpha, bk, out);
}

// Round 18
// 30.387 us; speedup vs baseline: 1.3461x; 1.0035x over previous
//
#include <hip/hip_runtime.h>
#include <hip/hip_bf16.h>
#include <math.h>

#define NNODES   100000
#define S        8192
#define D        8
#define EPSF     1e-6f
#define LOG2E    1.442695040888963f
#define EPS_S    (LOG2E * EPSF)
#define NT2      256        // 8192/32 tiles per dim

// ws byte offsets
#define ZBS_OFF  0          // 8192 rows x 8 ushort
#define U_OFF    131104     // 8192 f32
#define V_OFF    163872     // 8192 f32
#define ZB_OFF   196640     // 100000 rows x 8 bf16 = 1.6 MB
#define BK_OFF   1796736    // bucket region (128-aligned)
// bucket layout (128-B stride): dbuck[128] @0-127; sbuck[128] @128-255;
//   cbuck[128] @256-383; gdone @384  -> 385 slots

#define NDBLK    2048       // 64 chunk-pairs x 32 blocks
#define NL       258        // i-tiles per chunk-pair (2q+2) + (256-2q)

typedef __attribute__((ext_vector_type(8)))  short short8_t;
typedef __attribute__((ext_vector_type(16))) float f32x16;

// reduce two values across the block
__device__ __forceinline__ void block_reduce_2(float a, float b, float* sma,
                                               float* smb, float& ra, float& rb) {
    #pragma unroll
    for (int off = 32; off > 0; off >>= 1) {
        a += __shfl_down(a, off, 64);
        b += __shfl_down(b, off, 64);
    }
    int lane = threadIdx.x & 63, wid = threadIdx.x >> 6;
    if (lane == 0) { sma[wid] = a; smb[wid] = b; }
    __syncthreads();
    if (threadIdx.x == 0) {
        ra = 0.f; rb = 0.f;
        for (int w = 0; w < 4; ++w) { ra += sma[w]; rb += smb[w]; }
    }
}

// ---- kernel 1: sample-gather (prescaled RNE bf16, norms of ROUNDED values)
//      + full-Z bf16 copy; bucket init ----
__global__ __launch_bounds__(256) void gather_kernel(const float* __restrict__ Z,
                                                     const int* __restrict__ idx,
                                                     ushort* __restrict__ zbs,
                                                     float* __restrict__ u,
                                                     float* __restrict__ v,
                                                     ushort* __restrict__ zb16,
                                                     char* __restrict__ buckets) {
    int gid = blockIdx.x * 256 + threadIdx.x;

    if (gid < 385) {
        *(double*)(buckets + (size_t)gid * 128) = 0.0;
    }

    if (gid < S) {
        int n = idx[gid];
        const float4* zp = (const float4*)(Z + (size_t)n * D);
        float4 a = zp[0], b = zp[1];
        float z[8] = { a.x, a.y, a.z, a.w, b.x, b.y, b.z, b.w };
        float ss = 0.f;
        short8_t h;
        #pragma unroll
        for (int k = 0; k < 8; ++k) {
            float zs = LOG2E * z[k];
            __hip_bfloat16 hb = __float2bfloat16(zs);
            float hf = __bfloat162float(hb);
            ss = fmaf(hf, hf, ss);              // norm of the ROUNDED value
            h[k] = (short)__builtin_bit_cast(unsigned short, hb);
        }
        *(short8_t*)(zbs + (size_t)gid * 8) = h;
        u[gid] = ss + 8.f * EPS_S * EPS_S;
        v[gid] = ss;
    }

    if (gid < NNODES) {
        const float4* zp = (const float4*)(Z + (size_t)gid * D);
        float4 a = zp[0], b = zp[1];
        float z[8] = { a.x, a.y, a.z, a.w, b.x, b.y, b.z, b.w };
        short8_t o;
        #pragma unroll
        for (int k = 0; k < 8; ++k) {
            __hip_bfloat16 bb = __float2bfloat16(z[k]);
            o[k] = (short)__builtin_bit_cast(unsigned short, bb);
        }
        *(short8_t*)(zb16 + (size_t)gid * 8) = o;
    }
}

// bf16 row (uint4) -> 8 f32
#define UNPACK8(u4, f)                                        \
    f[0] = __uint_as_float(u4.x << 16);                       \
    f[1] = __uint_as_float(u4.x & 0xffff0000u);               \
    f[2] = __uint_as_float(u4.y << 16);                       \
    f[3] = __uint_as_float(u4.y & 0xffff0000u);               \
    f[4] = __uint_as_float(u4.z << 16);                       \
    f[5] = __uint_as_float(u4.z & 0xffff0000u);               \
    f[6] = __uint_as_float(u4.w << 16);                       \
    f[7] = __uint_as_float(u4.w & 0xffff0000u);

// One 32x32 tile-pair: MFMA + epilogue with weight wgt.
// C/D: col = lane&31, row = (reg&3) + 8*(reg>>2) + 4*(lane>>5).
__device__ __forceinline__ void accum32(short8_t af, short8_t bf, float vt,
                                        const float4* u4, float wgt,
                                        float& ax, float& ay, float& az, float& aw) {
    f32x16 c = { 0.f, 0.f, 0.f, 0.f, 0.f, 0.f, 0.f, 0.f,
                 0.f, 0.f, 0.f, 0.f, 0.f, 0.f, 0.f, 0.f };
    c = __builtin_amdgcn_mfma_f32_32x32x16_bf16(af, bf, c, 0, 0, 0);
    #pragma unroll
    for (int q = 0; q < 4; ++q) {
        float s0 = u4[q].x + vt, s1 = u4[q].y + vt;
        float s2 = u4[q].z + vt, s3 = u4[q].w + vt;
        float d0 = fmaf(c[4*q+0], -2.f, s0);
        float d1 = fmaf(c[4*q+1], -2.f, s1);
        float d2 = fmaf(c[4*q+2], -2.f, s2);
        float d3 = fmaf(c[4*q+3], -2.f, s3);
        ax = fmaf(wgt, __builtin_amdgcn_exp2f(-__builtin_amdgcn_sqrtf(__builtin_fabsf(d0))), ax);
        ay = fmaf(wgt, __builtin_amdgcn_exp2f(-__builtin_amdgcn_sqrtf(__builtin_fabsf(d1))), ay);
        az = fmaf(wgt, __builtin_amdgcn_exp2f(-__builtin_amdgcn_sqrtf(__builtin_fabsf(d2))), az);
        aw = fmaf(wgt, __builtin_amdgcn_exp2f(-__builtin_amdgcn_sqrtf(__builtin_fabsf(d3))), aw);
    }
}

// Process i-tiles [k0,k1) against the 2-tile j-chunk {jt0, jt0+1} whose
// B-fragments are in registers. tiOff maps k -> ti.
__device__ __forceinline__ void dense_segment(const ushort* __restrict__ zbs,
                                              const float* __restrict__ u,
                                              const float* __restrict__ vv,
                                              int k0, int k1, int tiOff, int jt0,
                                              int c31, int g,
                                              float& ax, float& ay, float& az, float& aw) {
    // B fragments for the chunk (g=1 lanes zeroed: they feed k-slots [8,16))
    short8_t zz = { 0,0,0,0,0,0,0,0 };
    short8_t b0 = *(const short8_t*)(zbs + (size_t)(jt0 * 32 + c31) * 8);
    short8_t b1 = *(const short8_t*)(zbs + (size_t)((jt0 + 1) * 32 + c31) * 8);
    if (g) { b0 = zz; b1 = zz; }
    float vt0 = vv[jt0 * 32 + c31];
    float vt1 = vv[(jt0 + 1) * 32 + c31];
    for (int k = k0; k < k1; ++k) {
        int ti = k - tiOff;
        short8_t af = *(const short8_t*)(zbs + (size_t)(ti * 32 + c31) * 8);
        float4 u4[4];
        #pragma unroll
        for (int q = 0; q < 4; ++q) u4[q] = *(const float4*)(u + ti * 32 + 8 * q + 4 * g);
        if (jt0 >= ti)
            accum32(af, b0, vt0, u4, (jt0 == ti) ? 1.f : 2.f, ax, ay, az, aw);
        if (jt0 + 1 >= ti)
            accum32(af, b1, vt1, u4, (jt0 + 1 == ti) ? 1.f : 2.f, ax, ay, az, aw);
    }
}

// ---- kernel 2: every block = thin sparse layer, then dense (B-in-registers);
//      bucketed atomic finalize carries both sums ----
__global__ __launch_bounds__(256, 6) void fused_kernel(
        const ushort* __restrict__ zbs, const float* __restrict__ u,
        const float* __restrict__ v, const ushort* __restrict__ zb16,
        const int* __restrict__ ei, const int* __restrict__ ej, int ne,
        const float* __restrict__ alpha, char* __restrict__ buckets,
        float* __restrict__ out) {
    __shared__ float reda[4], redb[4];
    __shared__ unsigned composeFlag;
    int tid = threadIdx.x, bx = blockIdx.x;

    // ---- phase A: sparse slice (4-edge chunks, 8 gathers in flight) ----
    float sacc = 0.f;
    {
        const uint4* zb = (const uint4*)zb16;
        int nchunk = ne >> 2;
        int stride = NDBLK * 256;
        for (int c = bx * 256 + tid; c < nchunk; c += stride) {
            int4 ia = ((const int4*)ei)[c];
            int4 ib = ((const int4*)ej)[c];
            int aidx[4] = { ia.x, ia.y, ia.z, ia.w };
            int bidx[4] = { ib.x, ib.y, ib.z, ib.w };
            uint4 ua[4], ub[4];
            #pragma unroll
            for (int q = 0; q < 4; ++q) { ua[q] = zb[aidx[q]]; ub[q] = zb[bidx[q]]; }
            #pragma unroll
            for (int q = 0; q < 4; ++q) {
                float fa[8], fb[8];
                UNPACK8(ua[q], fa);
                UNPACK8(ub[q], fb);
                float s2 = 0.f;
                #pragma unroll
                for (int k = 0; k < 8; ++k) {
                    float d = fa[k] - fb[k] + EPSF;
                    s2 = fmaf(d, d, s2);
                }
                sacc += __builtin_amdgcn_sqrtf(s2);
            }
        }
        for (int e = (nchunk << 2) + bx * 256 + tid; e < ne; e += stride) {
            uint4 ua = zb[ei[e]];
            uint4 ub = zb[ej[e]];
            float fa[8], fb[8];
            UNPACK8(ua, fa);
            UNPACK8(ub, fb);
            float s2 = 0.f;
            #pragma unroll
            for (int k = 0; k < 8; ++k) {
                float d = fa[k] - fb[k] + EPSF;
                s2 = fmaf(d, d, s2);
            }
            sacc += __builtin_amdgcn_sqrtf(s2);
        }
    }

    // ---- phase B: dense (chunk-paired columns, B-fragments in registers) ----
    int wave = tid >> 6, lane = tid & 63;
    int g = lane >> 5, c31 = lane & 31;

    int q  = bx >> 5;                  // chunk-pair [0,64)
    int wv = (bx & 31) * 4 + wave;     // wave-slice [0,128)
    int ja0 = 2 * q;                   // chunk A j-tiles {2q, 2q+1}
    int jb0 = 254 - 2 * q;             // chunk B j-tiles {254-2q, 255-2q}
    int nA  = 2 * q + 2;               // i-tiles in segment A

    int k0 = (wv * NL) >> 7;
    int k1 = ((wv + 1) * NL) >> 7;

    float ax = 0.f, ay = 0.f, az = 0.f, aw = 0.f;

    int eA = k1 < nA ? k1 : nA;
    if (k0 < eA)
        dense_segment(zbs, u, v, k0, eA, 0, ja0, c31, g, ax, ay, az, aw);
    int sB = k0 > nA ? k0 : nA;
    if (sB < k1)
        dense_segment(zbs, u, v, sB, k1, nA, jb0, c31, g, ax, ay, az, aw);

    float sd = 0.f, ss = 0.f;
    block_reduce_2((ax + ay) + (az + aw), sacc, reda, redb, sd, ss);

    // ---- bucketed finalize: 128+128 sum buckets (16-deep), 128 counters ----
    double* dbuck = (double*)(buckets);
    double* sbuck = (double*)(buckets + 128 * 128);
    unsigned* gdone = (unsigned*)(buckets + 384 * 128);

    if (tid == 0) {
        int b = bx & 127;
        (void)atomicAdd((double*)((char*)dbuck + b * 128), (double)sd);
        (void)atomicAdd((double*)((char*)sbuck + b * 128), (double)ss);
        __builtin_amdgcn_s_waitcnt(0);                 // both adds complete
        unsigned oc = atomicAdd((unsigned*)(buckets + (256 + (bx >> 4)) * 128), 1u);
        unsigned gg = 0xFFFFu;
        if (oc == 15u) {
            __builtin_amdgcn_s_waitcnt(0);
            gg = atomicAdd(gdone, 1u);
        }
        composeFlag = (gg == 127u) ? 1u : 0u;
    }
    __syncthreads();

    if (composeFlag) {
        __shared__ double acc2[2];
        int w = tid >> 6;
        double val = 0.0;
        if (w == 0) {
            val  = atomicAdd((double*)((char*)dbuck + lane * 128), 0.0);
            val += atomicAdd((double*)((char*)dbuck + (lane + 64) * 128), 0.0);
        } else if (w == 1) {
            val  = atomicAdd((double*)((char*)sbuck + lane * 128), 0.0);
            val += atomicAdd((double*)((char*)sbuck + (lane + 64) * 128), 0.0);
        }
        #pragma unroll
        for (int off = 32; off > 0; off >>= 1) val += __shfl_down(val, off, 64);
        if (w == 0 && lane == 0) acc2[0] = val;
        if (w == 1 && lane == 0) acc2[1] = val;
        __syncthreads();
        if (tid == 0) {
            double Dsum = acc2[0], Ssum = acc2[1];
            // diagonal entries are exp(-sqrt(8)*eps); subtract exactly
            double trace = (double)S * exp(-sqrt(8.0) * (double)EPSF);
            double offdiag = Dsum - trace;
            double a = (double)alpha[0];
            double z_pdist2 = (double)ne * a - Ssum;
            double z_pdist1 = exp(a) * 0.5 * 7.3890560989306495 * offdiag;
            out[0] = (float)(z_pdist2 - z_pdist1);
        }
    }
}

extern "C" void kernel_launch(void* const* d_in, const int* in_sizes, int n_in,
                              void* d_out, int out_size, void* d_ws, size_t ws_size,
                              hipStream_t stream) {
    const float* latent_Z = (const float*)d_in[0];
    const float* alpha    = (const float*)d_in[1];
    const int*   sidx     = (const int*)d_in[2];
    const int*   ei       = (const int*)d_in[3];
    const int*   ej       = (const int*)d_in[4];
    int ne = in_sizes[3];
    float* out = (float*)d_out;
    char*  ws  = (char*)d_ws;

    ushort* zbs   = (ushort*)(ws + ZBS_OFF);
    float*  u     = (float*)(ws + U_OFF);
    float*  v     = (float*)(ws + V_OFF);
    ushort* zb16  = (ushort*)(ws + ZB_OFF);
    char*   bk    = ws + BK_OFF;

    gather_kernel<<<(NNODES + 255) / 256, 256, 0, stream>>>(latent_Z, sidx,
                                                            zbs, u, v, zb16, bk);
    fused_kernel<<<NDBLK, 256, 0, stream>>>(zbs, u, v, zb16, ei, ej, ne,
                                            alpha, bk, out);
}